// Round 1
// baseline (886.143 us; speedup 1.0000x reference)
//
#include <hip/hip_runtime.h>
#include <math.h>

#define H      1024
#define NA     512
#define NI     256
#define SEQ    4096
#define BATCH  4
#define NTOK   (BATCH*SEQ)      // 16384
#define MTOK   32               // tokens per block in score kernel
#define KC     64               // K chunk staged in LDS
#define MP     36               // padded token stride (16B-aligned, conflict-free reads)
#define SINKN  4
#define RECENTN 19
#define MIDN   (SEQ - SINKN - RECENTN)   // 4073
#define KSEL   2025
#define CHK    16               // per-thread contiguous chunk in select kernel

// ---------------------------------------------------------------------------
// Kernel 1: fused two-layer MLP scores for att (keys) and imp (values).
// scores[b*S+s] = 0.6*sigmoid(relu(k@W1a+b1a)@W2a+b2a) + 0.4*(relu(v@W1i+b1i)@W2i+b2i)
// block = 256 threads, 32 tokens/block. Thread (to=tid&63, tt=tid>>6):
//   att units {to*4..+3} and {256+to*4..+3}, imp units {to*4..+3},
//   tokens {tt*8..+7}. 96 fp32 accumulators/thread.
// ---------------------------------------------------------------------------
__global__ __launch_bounds__(256) void score_kernel(
    const float* __restrict__ keys, const float* __restrict__ values,
    const float* __restrict__ W1a, const float* __restrict__ b1a,
    const float* __restrict__ W2a, const float* __restrict__ b2a,
    const float* __restrict__ W1i, const float* __restrict__ b1i,
    const float* __restrict__ W2i, const float* __restrict__ b2i,
    float* __restrict__ scores)
{
    // staging: 2*KC*MP = 4608 floats; reused in epilogue as 2*[32][65] = 4160
    __shared__ __align__(16) float smem[2 * KC * MP];
    float* k_lds = smem;
    float* v_lds = smem + KC * MP;

    const int tid  = threadIdx.x;
    const int to   = tid & 63;
    const int tt   = tid >> 6;
    const int tokb = blockIdx.x * MTOK;

    float accA0[4][8], accA1[4][8], accI[4][8];
#pragma unroll
    for (int j = 0; j < 4; ++j)
#pragma unroll
        for (int t = 0; t < 8; ++t) { accA0[j][t] = 0.f; accA1[j][t] = 0.f; accI[j][t] = 0.f; }

    // staging map: thread -> token tm = tid>>3, float4 slots q and q+8 of the 64-float chunk
    const int tm = tid >> 3;
    const int q  = tid & 7;
    const float* krow = keys   + (size_t)(tokb + tm) * H;
    const float* vrow = values + (size_t)(tokb + tm) * H;

    const float* wa_base = W1a + to * 4;
    const float* wi_base = W1i + to * 4;

    for (int h0 = 0; h0 < H; h0 += KC) {
        __syncthreads();
        float4 ka = *(const float4*)(krow + h0 + q * 4);
        float4 kb = *(const float4*)(krow + h0 + (q + 8) * 4);
        float4 va = *(const float4*)(vrow + h0 + q * 4);
        float4 vb = *(const float4*)(vrow + h0 + (q + 8) * 4);
        // transposed store: k_lds[i][tm] = keys[tm][h0+i]
        k_lds[(q * 4 + 0) * MP + tm] = ka.x;
        k_lds[(q * 4 + 1) * MP + tm] = ka.y;
        k_lds[(q * 4 + 2) * MP + tm] = ka.z;
        k_lds[(q * 4 + 3) * MP + tm] = ka.w;
        k_lds[((q + 8) * 4 + 0) * MP + tm] = kb.x;
        k_lds[((q + 8) * 4 + 1) * MP + tm] = kb.y;
        k_lds[((q + 8) * 4 + 2) * MP + tm] = kb.z;
        k_lds[((q + 8) * 4 + 3) * MP + tm] = kb.w;
        v_lds[(q * 4 + 0) * MP + tm] = va.x;
        v_lds[(q * 4 + 1) * MP + tm] = va.y;
        v_lds[(q * 4 + 2) * MP + tm] = va.z;
        v_lds[(q * 4 + 3) * MP + tm] = va.w;
        v_lds[((q + 8) * 4 + 0) * MP + tm] = vb.x;
        v_lds[((q + 8) * 4 + 1) * MP + tm] = vb.y;
        v_lds[((q + 8) * 4 + 2) * MP + tm] = vb.z;
        v_lds[((q + 8) * 4 + 3) * MP + tm] = vb.w;
        __syncthreads();

        const float* wa_p = wa_base + (size_t)h0 * NA;
        const float* wi_p = wi_base + (size_t)h0 * NI;
#pragma unroll 4
        for (int h = 0; h < KC; ++h) {
            float kf[8], vf[8], wa[8], wi4[4];
            *(float4*)&kf[0] = *(const float4*)&k_lds[h * MP + tt * 8];
            *(float4*)&kf[4] = *(const float4*)&k_lds[h * MP + tt * 8 + 4];
            *(float4*)&vf[0] = *(const float4*)&v_lds[h * MP + tt * 8];
            *(float4*)&vf[4] = *(const float4*)&v_lds[h * MP + tt * 8 + 4];
            *(float4*)&wa[0]  = *(const float4*)(wa_p + (size_t)h * NA);
            *(float4*)&wa[4]  = *(const float4*)(wa_p + (size_t)h * NA + 256);
            *(float4*)&wi4[0] = *(const float4*)(wi_p + (size_t)h * NI);
#pragma unroll
            for (int j = 0; j < 4; ++j)
#pragma unroll
                for (int t = 0; t < 8; ++t) {
                    accA0[j][t] = fmaf(kf[t], wa[j],     accA0[j][t]);
                    accA1[j][t] = fmaf(kf[t], wa[4 + j], accA1[j][t]);
                    accI[j][t]  = fmaf(vf[t], wi4[j],    accI[j][t]);
                }
        }
    }

    // ---- epilogue: second layers ----
    float b1aA[8], w2aA[8], b1iA[4], w2iA[4];
    *(float4*)&b1aA[0] = *(const float4*)(b1a + to * 4);
    *(float4*)&b1aA[4] = *(const float4*)(b1a + 256 + to * 4);
    *(float4*)&w2aA[0] = *(const float4*)(W2a + to * 4);
    *(float4*)&w2aA[4] = *(const float4*)(W2a + 256 + to * 4);
    *(float4*)&b1iA[0] = *(const float4*)(b1i + to * 4);
    *(float4*)&w2iA[0] = *(const float4*)(W2i + to * 4);

    __syncthreads();                      // done with staging LDS
    float* red_a = smem;                  // [32][65] padded
    float* red_i = smem + 32 * 65;

#pragma unroll
    for (int t = 0; t < 8; ++t) {
        float pa = 0.f, pi = 0.f;
#pragma unroll
        for (int j = 0; j < 4; ++j) {
            pa += fmaxf(accA0[j][t] + b1aA[j],     0.f) * w2aA[j];
            pa += fmaxf(accA1[j][t] + b1aA[4 + j], 0.f) * w2aA[4 + j];
            pi += fmaxf(accI[j][t]  + b1iA[j],     0.f) * w2iA[j];
        }
        const int tg = tt * 8 + t;
        red_a[tg * 65 + to] = pa;
        red_i[tg * 65 + to] = pi;
    }
    __syncthreads();
    if (tid < 32) {
        float sa = 0.f, si = 0.f;
        for (int j2 = 0; j2 < 64; ++j2) {
            sa += red_a[tid * 65 + j2];
            si += red_i[tid * 65 + j2];
        }
        const float att = 1.f / (1.f + expf(-(sa + b2a[0])));
        scores[tokb + tid] = 0.6f * att + 0.4f * (si + b2i[0]);
    }
}

// ---------------------------------------------------------------------------
// block-wide sum (256 threads), result broadcast to all threads
// ---------------------------------------------------------------------------
__device__ __forceinline__ int block_sum(int val, int* red, int tid)
{
#pragma unroll
    for (int off = 32; off > 0; off >>= 1) val += __shfl_down(val, off);
    if ((tid & 63) == 0) red[tid >> 6] = val;
    __syncthreads();
    const int total = red[0] + red[1] + red[2] + red[3];
    __syncthreads();
    return total;
}

// ---------------------------------------------------------------------------
// Kernel 2: per-row exact top-KSEL of the 4073 middle scores -> float mask.
// Radix (bitwise) select on sign-flipped uint32 keys; ties kept lowest-index
// first (top_k semantics). One block per batch row.
// ---------------------------------------------------------------------------
__global__ __launch_bounds__(256) void select_kernel(
    const float* __restrict__ scores, float* __restrict__ mask)
{
    __shared__ unsigned int ks[MIDN];
    __shared__ int red[4];
    __shared__ int scan_s[256];

    const int tid = threadIdx.x;
    const int row = blockIdx.x;
    const float* sr = scores + row * SEQ;

    for (int i = tid; i < MIDN; i += 256) {
        unsigned int u = __float_as_uint(sr[SINKN + i]);
        u = (u & 0x80000000u) ? ~u : (u | 0x80000000u);   // order-preserving map
        ks[i] = u;
    }
    __syncthreads();

    const int st = tid * CHK;
    const int en = (st + CHK < MIDN) ? (st + CHK) : MIDN;

    // max v with count(ks >= v) >= KSEL  ==> v is the KSEL-th largest value
    unsigned int v = 0;
    for (int bit = 31; bit >= 0; --bit) {
        const unsigned int cand = v | (1u << bit);
        int c = 0;
        for (int k = st; k < en; ++k) c += (ks[k] >= cand) ? 1 : 0;
        if (block_sum(c, red, tid) >= KSEL) v = cand;
    }

    int cgt = 0, ceq = 0;
    for (int k = st; k < en; ++k) { cgt += (ks[k] > v) ? 1 : 0; ceq += (ks[k] == v) ? 1 : 0; }
    const int total_gt = block_sum(cgt, red, tid);
    const int need = KSEL - total_gt;      // #ties to keep (>=1 by construction)

    scan_s[tid] = ceq;
    __syncthreads();
    if (tid == 0) {                        // exclusive scan of 256 tie counts
        int run = 0;
        for (int i = 0; i < 256; ++i) { const int t = scan_s[i]; scan_s[i] = run; run += t; }
    }
    __syncthreads();

    float* mr = mask + row * SEQ;
    int r = scan_s[tid];
    for (int k = st; k < en; ++k) {
        const unsigned int u = ks[k];
        bool keep = false;
        if (u > v) keep = true;
        else if (u == v) { keep = (r < need); ++r; }
        mr[SINKN + k] = keep ? 1.f : 0.f;
    }
    for (int s = tid; s < SEQ; s += 256) {
        if (s < SINKN || s >= SEQ - RECENTN) mr[s] = 1.f;
    }
}

// ---------------------------------------------------------------------------
// Kernel 3: out = concat(keys*mask, values*mask), float4 grid-stride.
// ---------------------------------------------------------------------------
__global__ __launch_bounds__(256) void apply_kernel(
    const float* __restrict__ keys, const float* __restrict__ values,
    const float* __restrict__ mask, float* __restrict__ out)
{
    const int QT = NTOK * H / 4;          // 4194304 float4 per tensor
    const int stride = gridDim.x * 256;
    for (int i4 = blockIdx.x * 256 + threadIdx.x; i4 < 2 * QT; i4 += stride) {
        const bool isv = (i4 >= QT);
        const int  j4  = isv ? (i4 - QT) : i4;
        const float m  = mask[j4 >> 8];   // 256 float4 per token row
        const float4* src = isv ? (const float4*)values : (const float4*)keys;
        const float4 x = src[j4];
        float4 y; y.x = x.x * m; y.y = x.y * m; y.z = x.z * m; y.w = x.w * m;
        ((float4*)out)[i4] = y;
    }
}

extern "C" void kernel_launch(void* const* d_in, const int* in_sizes, int n_in,
                              void* d_out, int out_size, void* d_ws, size_t ws_size,
                              hipStream_t stream)
{
    const float* keys   = (const float*)d_in[0];
    const float* values = (const float*)d_in[1];
    const float* W1a = (const float*)d_in[2];
    const float* b1a = (const float*)d_in[3];
    const float* W2a = (const float*)d_in[4];
    const float* b2a = (const float*)d_in[5];
    const float* W1i = (const float*)d_in[6];
    const float* b1i = (const float*)d_in[7];
    const float* W2i = (const float*)d_in[8];
    const float* b2i = (const float*)d_in[9];

    float* scores = (float*)d_ws;          // NTOK floats
    float* mask   = scores + NTOK;         // NTOK floats

    score_kernel<<<NTOK / MTOK, 256, 0, stream>>>(keys, values, W1a, b1a, W2a, b2a,
                                                  W1i, b1i, W2i, b2i, scores);
    select_kernel<<<BATCH, 256, 0, stream>>>(scores, mask);
    apply_kernel<<<8192, 256, 0, stream>>>(keys, values, mask, (float*)d_out);
}

// Round 2
// 821.077 us; speedup vs baseline: 1.0792x; 1.0792x over previous
//
#include <hip/hip_runtime.h>
#include <math.h>

#define H      1024
#define NA     512
#define NI     256
#define SEQ    4096
#define BATCH  4
#define NTOK   (BATCH*SEQ)      // 16384
#define MTOK   16               // tokens per block in score kernel
#define KC     64               // K chunk staged in LDS
#define PT     20               // padded token stride: 2-way write conflicts (free), 16B-aligned reads
#define SINKN  4
#define RECENTN 19
#define MIDN   (SEQ - SINKN - RECENTN)   // 4073
#define KSEL   2025
#define CHK    16               // per-thread contiguous chunk in select kernel

// ---------------------------------------------------------------------------
// Kernel 1: fused two-layer MLP scores for att (keys) and imp (values).
// scores[b*S+s] = 0.6*sigmoid(relu(k@W1a+b1a)@W2a+b2a) + 0.4*(relu(v@W1i+b1i)@W2i+b2i)
// block = 256 threads, 16 tokens/block (1024 blocks -> 4 blocks/CU).
// Thread (to=tid&63, tt=tid>>6): att units {to*4..+3} and {256+to*4..+3},
// imp units {to*4..+3}, tokens {tt*4..+3}. 48 fp32 accumulators/thread.
// ---------------------------------------------------------------------------
__global__ __launch_bounds__(256, 4) void score_kernel(
    const float* __restrict__ keys, const float* __restrict__ values,
    const float* __restrict__ W1a, const float* __restrict__ b1a,
    const float* __restrict__ W2a, const float* __restrict__ b2a,
    const float* __restrict__ W1i, const float* __restrict__ b1i,
    const float* __restrict__ W2i, const float* __restrict__ b2i,
    float* __restrict__ scores)
{
    // staging: 2*KC*PT = 2560 floats (10 KB); epilogue reuse: 2*[16][65] = 2080
    __shared__ __align__(16) float smem[2 * KC * PT];
    float* k_lds = smem;
    float* v_lds = smem + KC * PT;

    const int tid  = threadIdx.x;
    const int to   = tid & 63;
    const int tt   = tid >> 6;
    const int tokb = blockIdx.x * MTOK;

    float accA0[4][4], accA1[4][4], accI[4][4];
#pragma unroll
    for (int j = 0; j < 4; ++j)
#pragma unroll
        for (int t = 0; t < 4; ++t) { accA0[j][t] = 0.f; accA1[j][t] = 0.f; accI[j][t] = 0.f; }

    // staging map: thread -> token tm = tid&15, h-quad hq = tid>>4 (0..15)
    const int tm = tid & 15;
    const int hq = tid >> 4;
    const float* krow = keys   + (size_t)(tokb + tm) * H;
    const float* vrow = values + (size_t)(tokb + tm) * H;

    const float* wa_base = W1a + to * 4;
    const float* wi_base = W1i + to * 4;

    for (int h0 = 0; h0 < H; h0 += KC) {
        __syncthreads();
        float4 ka = *(const float4*)(krow + h0 + hq * 4);
        float4 va = *(const float4*)(vrow + h0 + hq * 4);
        // transposed store: k_lds[i][tm] = keys[tm][h0+i]; stride PT=20 -> 2-way (free)
        k_lds[(hq * 4 + 0) * PT + tm] = ka.x;
        k_lds[(hq * 4 + 1) * PT + tm] = ka.y;
        k_lds[(hq * 4 + 2) * PT + tm] = ka.z;
        k_lds[(hq * 4 + 3) * PT + tm] = ka.w;
        v_lds[(hq * 4 + 0) * PT + tm] = va.x;
        v_lds[(hq * 4 + 1) * PT + tm] = va.y;
        v_lds[(hq * 4 + 2) * PT + tm] = va.z;
        v_lds[(hq * 4 + 3) * PT + tm] = va.w;
        __syncthreads();

        const float* wa_p = wa_base + (size_t)h0 * NA;
        const float* wi_p = wi_base + (size_t)h0 * NI;
#pragma unroll 4
        for (int h = 0; h < KC; ++h) {
            float kf[4], vf[4], wa[8], wi4[4];
            *(float4*)&kf[0]  = *(const float4*)&k_lds[h * PT + tt * 4];
            *(float4*)&vf[0]  = *(const float4*)&v_lds[h * PT + tt * 4];
            *(float4*)&wa[0]  = *(const float4*)(wa_p + (size_t)h * NA);
            *(float4*)&wa[4]  = *(const float4*)(wa_p + (size_t)h * NA + 256);
            *(float4*)&wi4[0] = *(const float4*)(wi_p + (size_t)h * NI);
#pragma unroll
            for (int j = 0; j < 4; ++j)
#pragma unroll
                for (int t = 0; t < 4; ++t) {
                    accA0[j][t] = fmaf(kf[t], wa[j],     accA0[j][t]);
                    accA1[j][t] = fmaf(kf[t], wa[4 + j], accA1[j][t]);
                    accI[j][t]  = fmaf(vf[t], wi4[j],    accI[j][t]);
                }
        }
    }

    // ---- epilogue: second layers ----
    float b1aA[8], w2aA[8], b1iA[4], w2iA[4];
    *(float4*)&b1aA[0] = *(const float4*)(b1a + to * 4);
    *(float4*)&b1aA[4] = *(const float4*)(b1a + 256 + to * 4);
    *(float4*)&w2aA[0] = *(const float4*)(W2a + to * 4);
    *(float4*)&w2aA[4] = *(const float4*)(W2a + 256 + to * 4);
    *(float4*)&b1iA[0] = *(const float4*)(b1i + to * 4);
    *(float4*)&w2iA[0] = *(const float4*)(W2i + to * 4);

    __syncthreads();                      // done with staging LDS
    float* red_a = smem;                  // [16][65] padded
    float* red_i = smem + 16 * 65;

#pragma unroll
    for (int t = 0; t < 4; ++t) {
        float pa = 0.f, pi = 0.f;
#pragma unroll
        for (int j = 0; j < 4; ++j) {
            pa += fmaxf(accA0[j][t] + b1aA[j],     0.f) * w2aA[j];
            pa += fmaxf(accA1[j][t] + b1aA[4 + j], 0.f) * w2aA[4 + j];
            pi += fmaxf(accI[j][t]  + b1iA[j],     0.f) * w2iA[j];
        }
        const int tg = tt * 4 + t;
        red_a[tg * 65 + to] = pa;
        red_i[tg * 65 + to] = pi;
    }
    __syncthreads();
    if (tid < MTOK) {
        float sa = 0.f, si = 0.f;
        for (int j2 = 0; j2 < 64; ++j2) {
            sa += red_a[tid * 65 + j2];
            si += red_i[tid * 65 + j2];
        }
        const float att = 1.f / (1.f + expf(-(sa + b2a[0])));
        scores[tokb + tid] = 0.6f * att + 0.4f * (si + b2i[0]);
    }
}

// ---------------------------------------------------------------------------
// block-wide sum (256 threads), result broadcast to all threads
// ---------------------------------------------------------------------------
__device__ __forceinline__ int block_sum(int val, int* red, int tid)
{
#pragma unroll
    for (int off = 32; off > 0; off >>= 1) val += __shfl_down(val, off);
    if ((tid & 63) == 0) red[tid >> 6] = val;
    __syncthreads();
    const int total = red[0] + red[1] + red[2] + red[3];
    __syncthreads();
    return total;
}

// ---------------------------------------------------------------------------
// Kernel 2: per-row exact top-KSEL of the 4073 middle scores -> float mask.
// 4-pass byte-radix select (256-bin LDS histogram) on sign-flipped uint keys;
// ties kept lowest-index first (top_k semantics). One block per batch row.
// ---------------------------------------------------------------------------
__global__ __launch_bounds__(256) void select_kernel(
    const float* __restrict__ scores, float* __restrict__ mask)
{
    __shared__ unsigned int ks[MIDN];
    __shared__ int hist[256];
    __shared__ int red[4];
    __shared__ int scan_s[256];
    __shared__ unsigned int sh_pref;
    __shared__ int sh_r;

    const int tid = threadIdx.x;
    const int row = blockIdx.x;
    const float* sr = scores + row * SEQ;

    for (int i = tid; i < MIDN; i += 256) {
        unsigned int u = __float_as_uint(sr[SINKN + i]);
        u = (u & 0x80000000u) ? ~u : (u | 0x80000000u);   // order-preserving map
        ks[i] = u;
    }
    if (tid == 0) { sh_pref = 0u; sh_r = KSEL; }
    __syncthreads();

    // byte-radix: after 4 passes sh_pref == KSEL-th largest key value
    for (int b = 3; b >= 0; --b) {
        hist[tid] = 0;
        __syncthreads();
        const unsigned int hi_mask = (b == 3) ? 0u : (0xFFFFFFFFu << ((b + 1) * 8));
        const unsigned int pref = sh_pref;
        for (int i = tid; i < MIDN; i += 256) {
            const unsigned int u = ks[i];
            if ((u & hi_mask) == pref)
                atomicAdd(&hist[(u >> (b * 8)) & 255], 1);
        }
        __syncthreads();
        if (tid == 0) {
            int r = sh_r, cum = 0, d = 255;
            for (; d >= 0; --d) {
                cum += hist[d];
                if (cum >= r) break;
            }
            sh_r = r - (cum - hist[d]);
            sh_pref = sh_pref | ((unsigned int)d << (b * 8));
        }
        __syncthreads();
    }
    const unsigned int v = sh_pref;

    const int st = tid * CHK;
    const int en = (st + CHK < MIDN) ? (st + CHK) : MIDN;

    int cgt = 0, ceq = 0;
    for (int k = st; k < en; ++k) { cgt += (ks[k] > v) ? 1 : 0; ceq += (ks[k] == v) ? 1 : 0; }
    const int total_gt = block_sum(cgt, red, tid);
    const int need = KSEL - total_gt;      // #ties to keep (>=1 by construction)

    scan_s[tid] = ceq;
    __syncthreads();
    if (tid == 0) {                        // exclusive scan of 256 tie counts
        int run = 0;
        for (int i = 0; i < 256; ++i) { const int t = scan_s[i]; scan_s[i] = run; run += t; }
    }
    __syncthreads();

    float* mr = mask + row * SEQ;
    int r = scan_s[tid];
    for (int k = st; k < en; ++k) {
        const unsigned int u = ks[k];
        bool keep = false;
        if (u > v) keep = true;
        else if (u == v) { keep = (r < need); ++r; }
        mr[SINKN + k] = keep ? 1.f : 0.f;
    }
    for (int s = tid; s < SEQ; s += 256) {
        if (s < SINKN || s >= SEQ - RECENTN) mr[s] = 1.f;
    }
}

// ---------------------------------------------------------------------------
// Kernel 3: out = concat(keys*mask, values*mask), float4 grid-stride.
// ---------------------------------------------------------------------------
__global__ __launch_bounds__(256) void apply_kernel(
    const float* __restrict__ keys, const float* __restrict__ values,
    const float* __restrict__ mask, float* __restrict__ out)
{
    const int QT = NTOK * H / 4;          // 4194304 float4 per tensor
    const int stride = gridDim.x * 256;
    for (int i4 = blockIdx.x * 256 + threadIdx.x; i4 < 2 * QT; i4 += stride) {
        const bool isv = (i4 >= QT);
        const int  j4  = isv ? (i4 - QT) : i4;
        const float m  = mask[j4 >> 8];   // 256 float4 per token row
        const float4* src = isv ? (const float4*)values : (const float4*)keys;
        const float4 x = src[j4];
        float4 y; y.x = x.x * m; y.y = x.y * m; y.z = x.z * m; y.w = x.w * m;
        ((float4*)out)[i4] = y;
    }
}

extern "C" void kernel_launch(void* const* d_in, const int* in_sizes, int n_in,
                              void* d_out, int out_size, void* d_ws, size_t ws_size,
                              hipStream_t stream)
{
    const float* keys   = (const float*)d_in[0];
    const float* values = (const float*)d_in[1];
    const float* W1a = (const float*)d_in[2];
    const float* b1a = (const float*)d_in[3];
    const float* W2a = (const float*)d_in[4];
    const float* b2a = (const float*)d_in[5];
    const float* W1i = (const float*)d_in[6];
    const float* b1i = (const float*)d_in[7];
    const float* W2i = (const float*)d_in[8];
    const float* b2i = (const float*)d_in[9];

    float* scores = (float*)d_ws;          // NTOK floats
    float* mask   = scores + NTOK;         // NTOK floats

    score_kernel<<<NTOK / MTOK, 256, 0, stream>>>(keys, values, W1a, b1a, W2a, b2a,
                                                  W1i, b1i, W2i, b2i, scores);
    select_kernel<<<BATCH, 256, 0, stream>>>(scores, mask);
    apply_kernel<<<8192, 256, 0, stream>>>(keys, values, mask, (float*)d_out);
}